// Round 3
// baseline (303.079 us; speedup 1.0000x reference)
//
#include <hip/hip_runtime.h>
#include <math.h>

// 2D inverse DFT (+i sign, 1/512^2 scale) of 64 x 512 x 512 complex, then |.|.
// Register-resident 512-pt FFT per wave: 8 complex/lane (i = k*64 + lane).
// Pass 1 FFTs columns and stores DE-REVERSED into a transposed workspace
// ws_t[b][x][f] (f = natural Y-frequency): lane l owns the 8 consecutive
// f = rev6(l)*8 + rev3(k), so the store is 64 B contiguous per lane.
// Pass 2 stages ws_t columns through LDS, FFTs along X, writes |.| with the
// same contiguous-per-lane pattern. Output rows land in natural order.

#define TWO_PI_F 6.283185307179586f

__device__ __forceinline__ float2 cmul(float2 a, float2 b) {
    return make_float2(a.x * b.x - a.y * b.y, a.x * b.y + a.y * b.x);
}
__device__ __forceinline__ float2 cadd(float2 a, float2 b) { return make_float2(a.x + b.x, a.y + b.y); }
__device__ __forceinline__ float2 csub(float2 a, float2 b) { return make_float2(a.x - b.x, a.y - b.y); }
__device__ __forceinline__ float2 csq(float2 a) { return make_float2(a.x * a.x - a.y * a.y, 2.f * a.x * a.y); }
__device__ __forceinline__ unsigned rev6(unsigned v) { return __brev(v) >> 26; }

// In-place 512-pt inverse-sign DIF FFT. Lane l, regs k: element i = k*64 + l.
// On exit, position i holds X[rev9(i)]. A = exp(+2*pi*i*l/512).
// (validated in round 2 vs reference, absmax 6e-5)
__device__ __forceinline__ void fft512(float2* r, float2 A, int l) {
    const float S = 0.70710678118654752f;
    {   // stage d=256: pairs (k, k+4); w = A * exp(2*pi*i*k/8)
        float2 t0 = A;
        float2 t1 = cmul(A, make_float2(S, S));
        float2 t2 = make_float2(-A.y, A.x);
        float2 t3 = cmul(A, make_float2(-S, S));
        float2 u, v;
        u = r[0]; v = r[4]; r[0] = cadd(u, v); r[4] = cmul(csub(u, v), t0);
        u = r[1]; v = r[5]; r[1] = cadd(u, v); r[5] = cmul(csub(u, v), t1);
        u = r[2]; v = r[6]; r[2] = cadd(u, v); r[6] = cmul(csub(u, v), t2);
        u = r[3]; v = r[7]; r[3] = cadd(u, v); r[7] = cmul(csub(u, v), t3);
    }
    float2 A2 = csq(A);
    {   // stage d=128: pairs (k, k+2); w = A^2 * {1, i}
        float2 A2i = make_float2(-A2.y, A2.x);
        float2 u, v;
        u = r[0]; v = r[2]; r[0] = cadd(u, v); r[2] = cmul(csub(u, v), A2);
        u = r[1]; v = r[3]; r[1] = cadd(u, v); r[3] = cmul(csub(u, v), A2i);
        u = r[4]; v = r[6]; r[4] = cadd(u, v); r[6] = cmul(csub(u, v), A2);
        u = r[5]; v = r[7]; r[5] = cadd(u, v); r[7] = cmul(csub(u, v), A2i);
    }
    float2 A4 = csq(A2);
    {   // stage d=64: pairs (k, k+1); w = A^4
        float2 u, v;
        u = r[0]; v = r[1]; r[0] = cadd(u, v); r[1] = cmul(csub(u, v), A4);
        u = r[2]; v = r[3]; r[2] = cadd(u, v); r[3] = cmul(csub(u, v), A4);
        u = r[4]; v = r[5]; r[4] = cadd(u, v); r[5] = cmul(csub(u, v), A4);
        u = r[6]; v = r[7]; r[6] = cadd(u, v); r[7] = cmul(csub(u, v), A4);
    }
    // shuffle stages m = 32,16,8,4,2,1: hi lane: (own-other)*P, P = A^(256/m).
    float2 P = csq(A4);  // A^8
    #pragma unroll
    for (int mi = 0; mi < 6; ++mi) {
        const int m = 32 >> mi;
        const bool hi = (l & m) != 0;
        #pragma unroll
        for (int k = 0; k < 8; ++k) {
            float2 o;
            o.x = __shfl_xor(r[k].x, m);
            o.y = __shfl_xor(r[k].y, m);
            float2 sum = cadd(r[k], o);
            float2 dif = cmul(csub(r[k], o), P);
            r[k].x = hi ? dif.x : sum.x;
            r[k].y = hi ? dif.y : sum.y;
        }
        if (mi < 5) P = csq(P);
    }
}

// Pass 1: IFFT along Y. Block = 512 (8 waves); wave w owns column x0+w.
// grid = (64, 64). Front: float4 staged loads into transposed tile [c][y].
// Back: direct contiguous store to ws_t[b][x][f] (f natural, 64 B/lane).
__global__ __launch_bounds__(512)
void fft_y_kernel(const float2* __restrict__ in, float2* __restrict__ wst) {
    __shared__ float2 tile[8 * 512];   // [c][y], y swizzled by 4*(c>>1): 32 KiB
    const int t = threadIdx.x;
    const int w = t >> 6, l = t & 63;
    const int g = t & 3, q = t >> 2;   // staging: x-pair 2g..2g+1, row q
    const int x0 = blockIdx.x * 8;
    const int b  = blockIdx.y;

    const float2* src = in + ((size_t)b << 18) + x0;
    #pragma unroll
    for (int it = 0; it < 4; ++it) {
        const int y = it * 128 + q;
        const float4 v = *(const float4*)(src + ((size_t)y << 9) + 2 * g);
        const int ys = y ^ (4 * g);
        tile[(2 * g) * 512 + ys]     = make_float2(v.x, v.y);
        tile[(2 * g + 1) * 512 + ys] = make_float2(v.z, v.w);
    }
    __syncthreads();

    float sA, cA;
    sincosf(TWO_PI_F * (float)l * (1.0f / 512.0f), &sA, &cA);
    float2 r[8];
    const int sw = 4 * (w >> 1);
    #pragma unroll
    for (int k = 0; k < 8; ++k)
        r[k] = tile[w * 512 + ((k * 64 + l) ^ sw)];

    fft512(r, make_float2(cA, sA), l);

    // r[k] = Y-freq rev9(k*64+l) = rev6(l)*8 + rev3(k) of column x = x0+w.
    // De-reverse in addressing: f-offset rev3(k) -> reg order 0,4,2,6,1,5,3,7.
    float2* dst = wst + (((size_t)(b * 512 + x0 + w)) << 9) + rev6((unsigned)l) * 8;
    *(float4*)(dst + 0) = make_float4(r[0].x, r[0].y, r[4].x, r[4].y);
    *(float4*)(dst + 2) = make_float4(r[2].x, r[2].y, r[6].x, r[6].y);
    *(float4*)(dst + 4) = make_float4(r[1].x, r[1].y, r[5].x, r[5].y);
    *(float4*)(dst + 6) = make_float4(r[3].x, r[3].y, r[7].x, r[7].y);
}

// Pass 2: IFFT along X per f-row + magnitude. Block = 512 (8 waves);
// wave w owns row f0+w. grid = (64, 64). Staged loads from ws_t like pass 1.
__global__ __launch_bounds__(512)
void fft_x_mag_kernel(const float2* __restrict__ wst, float* __restrict__ out) {
    __shared__ float2 tile[8 * 512];   // [cf][x], x swizzled by 4*(cf>>1)
    const int t = threadIdx.x;
    const int w = t >> 6, l = t & 63;
    const int g = t & 3, q = t >> 2;   // staging: f-pair 2g..2g+1, x-row q
    const int f0 = blockIdx.x * 8;
    const int b  = blockIdx.y;

    const float2* src = wst + ((size_t)b << 18) + f0;
    #pragma unroll
    for (int it = 0; it < 4; ++it) {
        const int x = it * 128 + q;
        const float4 v = *(const float4*)(src + ((size_t)x << 9) + 2 * g);
        const int xs = x ^ (4 * g);
        tile[(2 * g) * 512 + xs]     = make_float2(v.x, v.y);
        tile[(2 * g + 1) * 512 + xs] = make_float2(v.z, v.w);
    }
    __syncthreads();

    float sA, cA;
    sincosf(TWO_PI_F * (float)l * (1.0f / 512.0f), &sA, &cA);
    float2 r[8];
    const int sw = 4 * (w >> 1);
    #pragma unroll
    for (int k = 0; k < 8; ++k)
        r[k] = tile[w * 512 + ((k * 64 + l) ^ sw)];

    fft512(r, make_float2(cA, sA), l);

    const float s = 1.0f / 262144.0f;
    // X-freq rev9(k*64+l) = rev6(l)*8 + rev3(k): lane owns 8 consecutive xf.
    float m0 = sqrtf(r[0].x * r[0].x + r[0].y * r[0].y) * s;  // off 0
    float m1 = sqrtf(r[4].x * r[4].x + r[4].y * r[4].y) * s;  // off 1
    float m2 = sqrtf(r[2].x * r[2].x + r[2].y * r[2].y) * s;  // off 2
    float m3 = sqrtf(r[6].x * r[6].x + r[6].y * r[6].y) * s;  // off 3
    float m4 = sqrtf(r[1].x * r[1].x + r[1].y * r[1].y) * s;  // off 4
    float m5 = sqrtf(r[5].x * r[5].x + r[5].y * r[5].y) * s;  // off 5
    float m6 = sqrtf(r[3].x * r[3].x + r[3].y * r[3].y) * s;  // off 6
    float m7 = sqrtf(r[7].x * r[7].x + r[7].y * r[7].y) * s;  // off 7

    float* orow = out + (((size_t)(b * 512 + f0 + w)) << 9) + rev6((unsigned)l) * 8;
    *(float4*)(orow + 0) = make_float4(m0, m1, m2, m3);
    *(float4*)(orow + 4) = make_float4(m4, m5, m6, m7);
}

extern "C" void kernel_launch(void* const* d_in, const int* in_sizes, int n_in,
                              void* d_out, int out_size, void* d_ws, size_t ws_size,
                              hipStream_t stream) {
    const float2* in = (const float2*)d_in[0];
    float2* wst = (float2*)d_ws;   // ws_t[b][x][f]: 64*512*512*8 = 128 MiB
    float* out = (float*)d_out;

    fft_y_kernel<<<dim3(64, 64), 512, 0, stream>>>(in, wst);
    fft_x_mag_kernel<<<dim3(64, 64), 512, 0, stream>>>(wst, out);
}

// Round 4
// 277.868 us; speedup vs baseline: 1.0907x; 1.0907x over previous
//
#include <hip/hip_runtime.h>
#include <hip/hip_fp16.h>
#include <math.h>

// 2D inverse DFT (+i sign, 1/512^2 scale) of 64 x 512 x 512 complex, then |.|.
// Register-resident 512-pt FFT per wave: 8 complex/lane (i = k*64 + lane).
// Pass 1 FFTs columns, scales by 1/512, stores DE-REVERSED as fp16 into a
// transposed workspace ws_h[b][x][f] (f natural): lane l owns the 8
// consecutive f = rev6(l)*8 + rev3(k) -> 32 B contiguous per lane.
// The 64 MiB fp16 intermediate fits the 256 MiB L3, so pass 2 reads mostly
// hit Infinity Cache. Pass 2 FFTs along X, applies the second 1/512 + |.|.

#define TWO_PI_F 6.283185307179586f

__device__ __forceinline__ float2 cmul(float2 a, float2 b) {
    return make_float2(a.x * b.x - a.y * b.y, a.x * b.y + a.y * b.x);
}
__device__ __forceinline__ float2 cadd(float2 a, float2 b) { return make_float2(a.x + b.x, a.y + b.y); }
__device__ __forceinline__ float2 csub(float2 a, float2 b) { return make_float2(a.x - b.x, a.y - b.y); }
__device__ __forceinline__ float2 csq(float2 a) { return make_float2(a.x * a.x - a.y * a.y, 2.f * a.x * a.y); }
__device__ __forceinline__ unsigned rev6(unsigned v) { return __brev(v) >> 26; }

// In-place 512-pt inverse-sign DIF FFT. Lane l, regs k: element i = k*64 + l.
// On exit, position i holds X[rev9(i)]. A = exp(+2*pi*i*l/512).
// (validated rounds 2-3 vs reference)
__device__ __forceinline__ void fft512(float2* r, float2 A, int l) {
    const float S = 0.70710678118654752f;
    {   // stage d=256: pairs (k, k+4); w = A * exp(2*pi*i*k/8)
        float2 t0 = A;
        float2 t1 = cmul(A, make_float2(S, S));
        float2 t2 = make_float2(-A.y, A.x);
        float2 t3 = cmul(A, make_float2(-S, S));
        float2 u, v;
        u = r[0]; v = r[4]; r[0] = cadd(u, v); r[4] = cmul(csub(u, v), t0);
        u = r[1]; v = r[5]; r[1] = cadd(u, v); r[5] = cmul(csub(u, v), t1);
        u = r[2]; v = r[6]; r[2] = cadd(u, v); r[6] = cmul(csub(u, v), t2);
        u = r[3]; v = r[7]; r[3] = cadd(u, v); r[7] = cmul(csub(u, v), t3);
    }
    float2 A2 = csq(A);
    {   // stage d=128: pairs (k, k+2); w = A^2 * {1, i}
        float2 A2i = make_float2(-A2.y, A2.x);
        float2 u, v;
        u = r[0]; v = r[2]; r[0] = cadd(u, v); r[2] = cmul(csub(u, v), A2);
        u = r[1]; v = r[3]; r[1] = cadd(u, v); r[3] = cmul(csub(u, v), A2i);
        u = r[4]; v = r[6]; r[4] = cadd(u, v); r[6] = cmul(csub(u, v), A2);
        u = r[5]; v = r[7]; r[5] = cadd(u, v); r[7] = cmul(csub(u, v), A2i);
    }
    float2 A4 = csq(A2);
    {   // stage d=64: pairs (k, k+1); w = A^4
        float2 u, v;
        u = r[0]; v = r[1]; r[0] = cadd(u, v); r[1] = cmul(csub(u, v), A4);
        u = r[2]; v = r[3]; r[2] = cadd(u, v); r[3] = cmul(csub(u, v), A4);
        u = r[4]; v = r[5]; r[4] = cadd(u, v); r[5] = cmul(csub(u, v), A4);
        u = r[6]; v = r[7]; r[6] = cadd(u, v); r[7] = cmul(csub(u, v), A4);
    }
    // shuffle stages m = 32,16,8,4,2,1: hi lane: (own-other)*P, P = A^(256/m).
    float2 P = csq(A4);  // A^8
    #pragma unroll
    for (int mi = 0; mi < 6; ++mi) {
        const int m = 32 >> mi;
        const bool hi = (l & m) != 0;
        #pragma unroll
        for (int k = 0; k < 8; ++k) {
            float2 o;
            o.x = __shfl_xor(r[k].x, m);
            o.y = __shfl_xor(r[k].y, m);
            float2 sum = cadd(r[k], o);
            float2 dif = cmul(csub(r[k], o), P);
            r[k].x = hi ? dif.x : sum.x;
            r[k].y = hi ? dif.y : sum.y;
        }
        if (mi < 5) P = csq(P);
    }
}

// Pass 1: IFFT along Y. Block = 512 (8 waves); wave w owns column x0+w.
// grid = (64, 64). Front: float4 staged loads into transposed tile [c][y].
// Back: scaled fp16 store to ws_h[b][x][f], 32 B contiguous per lane.
__global__ __launch_bounds__(512)
void fft_y_kernel(const float2* __restrict__ in, __half* __restrict__ wsh) {
    __shared__ float2 tile[8 * 512];   // [c][y], y swizzled by 4*(c>>1): 32 KiB
    const int t = threadIdx.x;
    const int w = t >> 6, l = t & 63;
    const int g = t & 3, q = t >> 2;   // staging: x-pair 2g..2g+1, row q
    const int x0 = blockIdx.x * 8;
    const int b  = blockIdx.y;

    const float2* src = in + ((size_t)b << 18) + x0;
    #pragma unroll
    for (int it = 0; it < 4; ++it) {
        const int y = it * 128 + q;
        const float4 v = *(const float4*)(src + ((size_t)y << 9) + 2 * g);
        const int ys = y ^ (4 * g);
        tile[(2 * g) * 512 + ys]     = make_float2(v.x, v.y);
        tile[(2 * g + 1) * 512 + ys] = make_float2(v.z, v.w);
    }
    __syncthreads();

    float sA, cA;
    sincosf(TWO_PI_F * (float)l * (1.0f / 512.0f), &sA, &cA);
    float2 r[8];
    const int sw = 4 * (w >> 1);
    #pragma unroll
    for (int k = 0; k < 8; ++k)
        r[k] = tile[w * 512 + ((k * 64 + l) ^ sw)];

    fft512(r, make_float2(cA, sA), l);

    // r[k] = Y-freq rev6(l)*8 + rev3(k) of column x = x0+w. De-reverse in
    // addressing; reg order for natural f: 0,4,2,6,1,5,3,7. Scale by 1/512.
    const float s = 1.0f / 512.0f;
    __half* dst = wsh + (((size_t)(b * 512 + x0 + w)) << 10) + rev6((unsigned)l) * 16;
    union { uint4 u; __half2 h[4]; } a0, a1;
    a0.h[0] = __floats2half2_rn(r[0].x * s, r[0].y * s);
    a0.h[1] = __floats2half2_rn(r[4].x * s, r[4].y * s);
    a0.h[2] = __floats2half2_rn(r[2].x * s, r[2].y * s);
    a0.h[3] = __floats2half2_rn(r[6].x * s, r[6].y * s);
    a1.h[0] = __floats2half2_rn(r[1].x * s, r[1].y * s);
    a1.h[1] = __floats2half2_rn(r[5].x * s, r[5].y * s);
    a1.h[2] = __floats2half2_rn(r[3].x * s, r[3].y * s);
    a1.h[3] = __floats2half2_rn(r[7].x * s, r[7].y * s);
    *(uint4*)dst       = a0.u;
    *(uint4*)(dst + 8) = a1.u;
}

// Pass 2: IFFT along X per f-row + magnitude. Block = 512 (8 waves);
// wave w owns row f0+w. grid = (64, 64). fp16 LDS tile, conflict-free
// (4-B elements, lane-consecutive addressing) -> no swizzle needed.
__global__ __launch_bounds__(512)
void fft_x_mag_kernel(const __half* __restrict__ wsh, float* __restrict__ out) {
    __shared__ uint tile[8 * 512];     // tile[j*512+x] = half2 cplx (x, f0+j): 16 KiB
    const int t = threadIdx.x;
    const int w = t >> 6, l = t & 63;
    const int f0 = blockIdx.x * 8;
    const int b  = blockIdx.y;

    // staging: thread t owns x = t; its 8-f chunk is 32 B contiguous.
    {
        const __half* src = wsh + ((size_t)b << 19) + ((size_t)t << 10) + f0 * 2;
        const uint4 ua = *(const uint4*)(src);
        const uint4 ub = *(const uint4*)(src + 8);
        tile[0 * 512 + t] = ua.x;
        tile[1 * 512 + t] = ua.y;
        tile[2 * 512 + t] = ua.z;
        tile[3 * 512 + t] = ua.w;
        tile[4 * 512 + t] = ub.x;
        tile[5 * 512 + t] = ub.y;
        tile[6 * 512 + t] = ub.z;
        tile[7 * 512 + t] = ub.w;
    }
    __syncthreads();

    float sA, cA;
    sincosf(TWO_PI_F * (float)l * (1.0f / 512.0f), &sA, &cA);
    float2 r[8];
    #pragma unroll
    for (int k = 0; k < 8; ++k) {
        uint p = tile[w * 512 + k * 64 + l];
        r[k] = __half22float2(*(const __half2*)&p);
    }

    fft512(r, make_float2(cA, sA), l);

    const float s = 1.0f / 512.0f;   // second half of 1/512^2
    // X-freq rev9(k*64+l) = rev6(l)*8 + rev3(k): lane owns 8 consecutive xf.
    float m0 = sqrtf(r[0].x * r[0].x + r[0].y * r[0].y) * s;  // off 0
    float m1 = sqrtf(r[4].x * r[4].x + r[4].y * r[4].y) * s;  // off 1
    float m2 = sqrtf(r[2].x * r[2].x + r[2].y * r[2].y) * s;  // off 2
    float m3 = sqrtf(r[6].x * r[6].x + r[6].y * r[6].y) * s;  // off 3
    float m4 = sqrtf(r[1].x * r[1].x + r[1].y * r[1].y) * s;  // off 4
    float m5 = sqrtf(r[5].x * r[5].x + r[5].y * r[5].y) * s;  // off 5
    float m6 = sqrtf(r[3].x * r[3].x + r[3].y * r[3].y) * s;  // off 6
    float m7 = sqrtf(r[7].x * r[7].x + r[7].y * r[7].y) * s;  // off 7

    float* orow = out + (((size_t)(b * 512 + f0 + w)) << 9) + rev6((unsigned)l) * 8;
    *(float4*)(orow + 0) = make_float4(m0, m1, m2, m3);
    *(float4*)(orow + 4) = make_float4(m4, m5, m6, m7);
}

extern "C" void kernel_launch(void* const* d_in, const int* in_sizes, int n_in,
                              void* d_out, int out_size, void* d_ws, size_t ws_size,
                              hipStream_t stream) {
    const float2* in = (const float2*)d_in[0];
    __half* wsh = (__half*)d_ws;   // ws_h[b][x][f] fp16: 64*512*512*4 = 64 MiB
    float* out = (float*)d_out;

    fft_y_kernel<<<dim3(64, 64), 512, 0, stream>>>(in, wsh);
    fft_x_mag_kernel<<<dim3(64, 64), 512, 0, stream>>>(wsh, out);
}